// Round 10
// baseline (389.363 us; speedup 1.0000x reference)
//
#include <hip/hip_runtime.h>

#define HH 4  // heads

__device__ __forceinline__ float lrelu(float v){ return v > 0.f ? v : 0.2f*v; }

// h = X @ W  (W is [IC, 64] row-major), plus per-head attention logits (C=16).
// 256-thread block = 4 waves, one node per wave. Compile-time IC for unroll.
template<int IC>
__global__ void gemm_gat(const float* __restrict__ X, const float* __restrict__ W,
                         const float* __restrict__ a_s, const float* __restrict__ a_d,
                         float* __restrict__ h, float* __restrict__ als, float* __restrict__ ald,
                         int N) {
    int t = threadIdx.x, lane = t & 63, wid = t >> 6;
    int n = blockIdx.x*4 + wid;
    bool valid = n < N;
    int nc = valid ? n : N-1;
    __shared__ float xs[4][IC];
    #pragma unroll
    for (int k = lane; k < IC; k += 64) xs[wid][k] = X[(size_t)nc*IC + k];
    float acc = 0.f;
    #pragma unroll 8
    for (int k = 0; k < IC; ++k) acc += xs[wid][k] * W[k*64 + lane];
    if (valid) h[(size_t)nc*64 + lane] = acc;
    int hh = lane >> 4, c = lane & 15;
    float ps = acc * a_s[hh*16 + c];
    float pd = acc * a_d[hh*16 + c];
    #pragma unroll
    for (int m = 1; m < 16; m <<= 1){ ps += __shfl_xor(ps, m); pd += __shfl_xor(pd, m); }
    if (valid && c == 0){ als[nc*HH + hh] = ps; ald[nc*HH + hh] = pd; }
}

// ---------------- CSR build ----------------

__global__ void zero_i32(int* __restrict__ p, int n){
    int i = blockIdx.x*256 + threadIdx.x;
    if (i < n) p[i] = 0;
}

__global__ void count_deg(const int* __restrict__ ei, int* __restrict__ deg, int E){
    int e = blockIdx.x*256 + threadIdx.x;
    if (e < E) atomicAdd(&deg[ei[E + e]], 1);
}

__global__ void deg_bsum(const int* __restrict__ deg, int* __restrict__ bsum, int N){
    int t = threadIdx.x;
    int base = blockIdx.x*1024 + t*4;
    int s = 0;
    if (base + 3 < N){
        int4 v = *(const int4*)(deg + base);
        s = v.x + v.y + v.z + v.w;
    } else {
        for (int q = 0; q < 4; ++q) if (base + q < N) s += deg[base + q];
    }
    #pragma unroll
    for (int m = 1; m < 64; m <<= 1) s += __shfl_xor(s, m);
    __shared__ int ws[4];
    if ((t & 63) == 0) ws[t >> 6] = s;
    __syncthreads();
    if (t == 0) bsum[blockIdx.x] = ws[0] + ws[1] + ws[2] + ws[3];
}

__global__ void scan_write(const int* __restrict__ deg, const int* __restrict__ bsum,
                           int* __restrict__ row_off, int* __restrict__ cursor, int N, int E){
    int t = threadIdx.x, bid = blockIdx.x, lane = t & 63, w = t >> 6;
    int base = bid*1024 + t*4;
    int v0 = 0, v1 = 0, v2 = 0, v3 = 0;
    if (base + 3 < N){
        int4 v = *(const int4*)(deg + base);
        v0 = v.x; v1 = v.y; v2 = v.z; v3 = v.w;
    } else {
        if (base     < N) v0 = deg[base];
        if (base + 1 < N) v1 = deg[base + 1];
        if (base + 2 < N) v2 = deg[base + 2];
        if (base + 3 < N) v3 = deg[base + 3];
    }
    int s = v0 + v1 + v2 + v3;
    int x = s;
    #pragma unroll
    for (int d = 1; d < 64; d <<= 1){
        int y = __shfl_up(x, d);
        if (lane >= d) x += y;
    }
    __shared__ int wsum[4];
    __shared__ int boff_s;
    if (lane == 63) wsum[w] = x;
    if (t < 64){
        int o = 0;
        for (int i = t; i < bid; i += 64) o += bsum[i];
        #pragma unroll
        for (int m = 1; m < 64; m <<= 1) o += __shfl_xor(o, m);
        if (t == 0) boff_s = o;
    }
    __syncthreads();
    int woff = 0;
    for (int i = 0; i < w; ++i) woff += wsum[i];
    int o = boff_s + woff + (x - s);
    if (base     < N){ row_off[base]     = o; cursor[base]     = o; o += v0; }
    if (base + 1 < N){ row_off[base + 1] = o; cursor[base + 1] = o; o += v1; }
    if (base + 2 < N){ row_off[base + 2] = o; cursor[base + 2] = o; o += v2; }
    if (base + 3 < N){ row_off[base + 3] = o; cursor[base + 3] = o; o += v3; }
    if (t == 0 && bid == 0) row_off[N] = E;
}

__global__ void fill_csr(const int* __restrict__ ei, int* __restrict__ cursor,
                         int* __restrict__ ssrc, int E){
    int e = blockIdx.x*256 + threadIdx.x;
    if (e < E){
        int d = ei[E + e];
        int p = atomicAdd(&cursor[d], 1);
        ssrc[p] = ei[e];
    }
}

// ---------------- layer-3 prep ----------------
__global__ void prep_l3(const float* __restrict__ W3, const float* __restrict__ a3s,
                        const float* __restrict__ a3d, float* __restrict__ ws3,
                        float* __restrict__ wd3, float* __restrict__ W3p){
    int t = threadIdx.x;          // 256 = (hh,k)
    int hh = t >> 6, k = t & 63;
    float ss = 0.f, sd = 0.f;
    for (int c = 0; c < 64; ++c){
        float w = W3[k*256 + hh*64 + c];
        ss += w * a3s[hh*64 + c];
        sd += w * a3d[hh*64 + c];
        W3p[t*64 + c] = 0.25f * w;
    }
    ws3[t] = ss; wd3[t] = sd;
}

// ================= layer-1 aggregation + BN/ELU + FUSED layer-2 transform =================
// 4 nodes/block, one wave per node. Gather: 16 slots per chunk, 4 dwordx4 in flight.
// Self-seed MUST be group-0-only (lane<16): the m=16,32 butterfly sums the 4 groups.
__global__ void gat_agg16_l1(const int* __restrict__ row_off, const int* __restrict__ ssrc,
                             const float* __restrict__ als, const float* __restrict__ ald,
                             const float* __restrict__ h, const float* __restrict__ b,
                             const float* __restrict__ g, const float* __restrict__ bb,
                             const float* __restrict__ bm, const float* __restrict__ bv,
                             const float* __restrict__ W2, const float* __restrict__ a2s,
                             const float* __restrict__ a2d, float* __restrict__ h2,
                             float* __restrict__ als2, float* __restrict__ ald2, int N){
    int t = threadIdx.x, lane = t & 63, wid = t >> 6;
    __shared__ float wl[4][16][4];   // [wave][edge][head]
    __shared__ int   sl[4][16];
    __shared__ __align__(16) float vb[4][64];
    int n = blockIdx.x*4 + wid;
    if (n >= N) return;              // no cross-wave LDS use; safe
    int j  = lane & 15;   // weight-phase edge slot
    int hh = lane >> 4;   // weight-phase head
    int cb = lane & 15;   // channel block (4 ch)
    int gq = lane >> 4;   // gather edge-group
    int hd = cb >> 2;     // head of my channels
    float ad_w = ald[n*HH + hh];
    float v_hd = __expf(lrelu(als[n*HH + hd] + ald[n*HH + hd]));
    int beg = row_off[n], end = row_off[n+1];
    float4 acc = make_float4(0.f, 0.f, 0.f, 0.f);
    if (lane < 16){   // seed self-loop in group 0 ONLY (butterfly sums groups)
        float4 hs = *(const float4*)(h + (size_t)n*64 + cb*4);
        acc.x = v_hd*hs.x; acc.y = v_hd*hs.y; acc.z = v_hd*hs.z; acc.w = v_hd*hs.w;
    }
    float denp = 0.f;
    for (int c16 = beg; c16 < end; c16 += 16){
        int e = c16 + j;
        int s = n; float ev = 0.f;
        if (e < end){ s = ssrc[e]; ev = __expf(lrelu(als[s*HH + hh] + ad_w)); }
        denp += ev;
        wl[wid][j][hh] = ev;
        if (hh == 0) sl[wid][j] = s;
        // all 16 slots unconditionally (dead slots: w=0, s=self -> L1-hot)
        int   s0 = sl[wid][gq],     s1 = sl[wid][4+gq];
        int   s2 = sl[wid][8+gq],   s3 = sl[wid][12+gq];
        float w0 = wl[wid][gq][hd], w1 = wl[wid][4+gq][hd];
        float w2 = wl[wid][8+gq][hd], w3 = wl[wid][12+gq][hd];
        float4 h0 = *(const float4*)(h + (size_t)s0*64 + cb*4);
        float4 h1 = *(const float4*)(h + (size_t)s1*64 + cb*4);
        float4 h2v = *(const float4*)(h + (size_t)s2*64 + cb*4);
        float4 h3 = *(const float4*)(h + (size_t)s3*64 + cb*4);
        acc.x += w0*h0.x + w1*h1.x + w2*h2v.x + w3*h3.x;
        acc.y += w0*h0.y + w1*h1.y + w2*h2v.y + w3*h3.y;
        acc.z += w0*h0.z + w1*h1.z + w2*h2v.z + w3*h3.z;
        acc.w += w0*h0.w + w1*h1.w + w2*h2v.w + w3*h3.w;
    }
    #pragma unroll
    for (int m = 1; m < 16; m <<= 1) denp += __shfl_xor(denp, m);
    float den = __shfl(denp, hd << 4) + v_hd;
    #pragma unroll
    for (int m = 16; m < 64; m <<= 1){
        acc.x += __shfl_xor(acc.x, m); acc.y += __shfl_xor(acc.y, m);
        acc.z += __shfl_xor(acc.z, m); acc.w += __shfl_xor(acc.w, m);
    }
    float4 bb4 = *(const float4*)(b  + cb*4);
    float4 gg4 = *(const float4*)(g  + cb*4);
    float4 be4 = *(const float4*)(bb + cb*4);
    float4 bm4 = *(const float4*)(bm + cb*4);
    float4 bv4 = *(const float4*)(bv + cb*4);
    float4 val;
    val.x = gg4.x*(acc.x/den + bb4.x - bm4.x)*rsqrtf(bv4.x + 1e-5f) + be4.x;
    val.y = gg4.y*(acc.y/den + bb4.y - bm4.y)*rsqrtf(bv4.y + 1e-5f) + be4.y;
    val.z = gg4.z*(acc.z/den + bb4.z - bm4.z)*rsqrtf(bv4.z + 1e-5f) + be4.z;
    val.w = gg4.w*(acc.w/den + bb4.w - bm4.w)*rsqrtf(bv4.w + 1e-5f) + be4.w;
    val.x = val.x > 0.f ? val.x : expm1f(val.x);
    val.y = val.y > 0.f ? val.y : expm1f(val.y);
    val.z = val.z > 0.f ? val.z : expm1f(val.z);
    val.w = val.w > 0.f ? val.w : expm1f(val.w);
    if (lane < 16) *(float4*)&vb[wid][cb*4] = val;   // same-wave produce/consume
    // ---- fused layer-2 transform: h2row[lane] = vb . W2[:,lane] ----
    float acc2 = 0.f;
    #pragma unroll 8
    for (int k = 0; k < 64; ++k) acc2 += vb[wid][k] * W2[k*64 + lane];
    h2[(size_t)n*64 + lane] = acc2;
    float ps = acc2 * a2s[hh*16 + j];
    float pd = acc2 * a2d[hh*16 + j];
    #pragma unroll
    for (int m = 1; m < 16; m <<= 1){ ps += __shfl_xor(ps, m); pd += __shfl_xor(pd, m); }
    if (j == 0){ als2[n*HH + hh] = ps; ald2[n*HH + hh] = pd; }
}

// ---------------- layer-2 aggregation + BN/ELU + layer-3 logits ----------------
__global__ void gat_agg16_l2(const int* __restrict__ row_off, const int* __restrict__ ssrc,
                             const float* __restrict__ als, const float* __restrict__ ald,
                             const float* __restrict__ h, const float* __restrict__ b,
                             const float* __restrict__ g, const float* __restrict__ bb,
                             const float* __restrict__ bm, const float* __restrict__ bv,
                             float* __restrict__ out,
                             const float* __restrict__ ws3, const float* __restrict__ wd3,
                             float* __restrict__ als3, float* __restrict__ ald3, int N){
    int t = threadIdx.x, lane = t & 63, wid = t >> 6;
    int n = blockIdx.x*4 + wid;
    if (n >= N) return;
    __shared__ float wl[4][16][4];
    __shared__ int   sl[4][16];
    int j  = lane & 15;
    int hh = lane >> 4;
    int cb = lane & 15;
    int gq = lane >> 4;
    int hd = cb >> 2;
    float ad_w = ald[n*HH + hh];
    float v_hd = __expf(lrelu(als[n*HH + hd] + ald[n*HH + hd]));
    int beg = row_off[n], end = row_off[n+1];
    float4 acc = make_float4(0.f, 0.f, 0.f, 0.f);
    if (lane < 16){   // seed self-loop in group 0 ONLY
        float4 hs = *(const float4*)(h + (size_t)n*64 + cb*4);
        acc.x = v_hd*hs.x; acc.y = v_hd*hs.y; acc.z = v_hd*hs.z; acc.w = v_hd*hs.w;
    }
    float denp = 0.f;
    for (int c16 = beg; c16 < end; c16 += 16){
        int e = c16 + j;
        int s = n; float ev = 0.f;
        if (e < end){ s = ssrc[e]; ev = __expf(lrelu(als[s*HH + hh] + ad_w)); }
        denp += ev;
        wl[wid][j][hh] = ev;
        if (hh == 0) sl[wid][j] = s;
        int   s0 = sl[wid][gq],     s1 = sl[wid][4+gq];
        int   s2 = sl[wid][8+gq],   s3 = sl[wid][12+gq];
        float w0 = wl[wid][gq][hd], w1 = wl[wid][4+gq][hd];
        float w2 = wl[wid][8+gq][hd], w3 = wl[wid][12+gq][hd];
        float4 h0 = *(const float4*)(h + (size_t)s0*64 + cb*4);
        float4 h1 = *(const float4*)(h + (size_t)s1*64 + cb*4);
        float4 h2v = *(const float4*)(h + (size_t)s2*64 + cb*4);
        float4 h3 = *(const float4*)(h + (size_t)s3*64 + cb*4);
        acc.x += w0*h0.x + w1*h1.x + w2*h2v.x + w3*h3.x;
        acc.y += w0*h0.y + w1*h1.y + w2*h2v.y + w3*h3.y;
        acc.z += w0*h0.z + w1*h1.z + w2*h2v.z + w3*h3.z;
        acc.w += w0*h0.w + w1*h1.w + w2*h2v.w + w3*h3.w;
    }
    #pragma unroll
    for (int m = 1; m < 16; m <<= 1) denp += __shfl_xor(denp, m);
    float den = __shfl(denp, hd << 4) + v_hd;
    #pragma unroll
    for (int m = 16; m < 64; m <<= 1){
        acc.x += __shfl_xor(acc.x, m); acc.y += __shfl_xor(acc.y, m);
        acc.z += __shfl_xor(acc.z, m); acc.w += __shfl_xor(acc.w, m);
    }
    float4 bb4 = *(const float4*)(b  + cb*4);
    float4 gg4 = *(const float4*)(g  + cb*4);
    float4 be4 = *(const float4*)(bb + cb*4);
    float4 bm4 = *(const float4*)(bm + cb*4);
    float4 bv4 = *(const float4*)(bv + cb*4);
    float4 val;
    val.x = gg4.x*(acc.x/den + bb4.x - bm4.x)*rsqrtf(bv4.x + 1e-5f) + be4.x;
    val.y = gg4.y*(acc.y/den + bb4.y - bm4.y)*rsqrtf(bv4.y + 1e-5f) + be4.y;
    val.z = gg4.z*(acc.z/den + bb4.z - bm4.z)*rsqrtf(bv4.z + 1e-5f) + be4.z;
    val.w = gg4.w*(acc.w/den + bb4.w - bm4.w)*rsqrtf(bv4.w + 1e-5f) + be4.w;
    val.x = val.x > 0.f ? val.x : expm1f(val.x);
    val.y = val.y > 0.f ? val.y : expm1f(val.y);
    val.z = val.z > 0.f ? val.z : expm1f(val.z);
    val.w = val.w > 0.f ? val.w : expm1f(val.w);
    if (lane < 16) *(float4*)(out + (size_t)n*64 + cb*4) = val;
    // layer-3 logits: group gq computes head gq from full row
    float4 w_s = *(const float4*)(ws3 + gq*64 + cb*4);
    float4 w_d = *(const float4*)(wd3 + gq*64 + cb*4);
    float ps = val.x*w_s.x + val.y*w_s.y + val.z*w_s.z + val.w*w_s.w;
    float pd = val.x*w_d.x + val.y*w_d.y + val.z*w_d.z + val.w*w_d.w;
    #pragma unroll
    for (int m = 1; m < 16; m <<= 1){ ps += __shfl_xor(ps, m); pd += __shfl_xor(pd, m); }
    if (cb == 0){ als3[n*HH + gq] = ps; ald3[n*HH + gq] = pd; }
}

// ===== layer-3: aggregate hin (4 heads) + coop GEMM W3p + BN + FUSED classifier =====
__global__ void gat_agg3_fused(const int* __restrict__ row_off, const int* __restrict__ ssrc,
                               const float* __restrict__ als, const float* __restrict__ ald,
                               const float* __restrict__ hin, const float* __restrict__ W3p,
                               const float* __restrict__ b, const float* __restrict__ g,
                               const float* __restrict__ bb, const float* __restrict__ bm,
                               const float* __restrict__ bv,
                               const float* __restrict__ cW1, const float* __restrict__ cb1,
                               const float* __restrict__ cW2, const float* __restrict__ cb2,
                               float* __restrict__ dout, int N){
    int t = threadIdx.x, lane = t & 63, wid = t >> 6;
    int n0 = blockIdx.x*4;
    int n = min(n0 + wid, N-1);          // clamp; no early return (syncthreads below)
    bool valid = (n0 + wid) < N;
    __shared__ __align__(16) float4 wlds[4][64];
    __shared__ int slds[4][64];
    __shared__ __align__(16) float ysh[4*256];
    __shared__ float red[4][4][64];      // [wave][node][lane]
    __shared__ float cls1[64*32];        // cW1, 8 KB
    __shared__ float clb[32], clw2[32];
    __shared__ float ysc[4][64];
    for (int k = t; k < 2048; k += 256) cls1[k] = cW1[k];
    if (t < 32){ clb[t] = cb1[t]; clw2[t] = cW2[t]; }
    int cb = lane & 15, gq = lane >> 4;
    float4 adv = *(const float4*)(ald + n*4);
    float4 av  = *(const float4*)(als + n*4);
    float v0 = __expf(lrelu(av.x + adv.x)), v1 = __expf(lrelu(av.y + adv.y));
    float v2 = __expf(lrelu(av.z + adv.z)), v3 = __expf(lrelu(av.w + adv.w));
    int beg = row_off[n], end = row_off[n+1];
    float4 acc0 = make_float4(0,0,0,0), acc1 = acc0, acc2 = acc0, acc3 = acc0;
    if (lane < 16){   // seed self-loop in group 0 ONLY
        float4 hs = *(const float4*)(hin + (size_t)n*64 + cb*4);
        acc0.x = v0*hs.x; acc0.y = v0*hs.y; acc0.z = v0*hs.z; acc0.w = v0*hs.w;
        acc1.x = v1*hs.x; acc1.y = v1*hs.y; acc1.z = v1*hs.z; acc1.w = v1*hs.w;
        acc2.x = v2*hs.x; acc2.y = v2*hs.y; acc2.z = v2*hs.z; acc2.w = v2*hs.w;
        acc3.x = v3*hs.x; acc3.y = v3*hs.y; acc3.z = v3*hs.z; acc3.w = v3*hs.w;
    }
    float dp0 = 0.f, dp1 = 0.f, dp2 = 0.f, dp3 = 0.f;
    for (int c64 = beg; c64 < end; c64 += 64){
        int e = c64 + lane;
        int s = n; float e0 = 0.f, e1 = 0.f, e2 = 0.f, e3 = 0.f;
        if (e < end){
            s = ssrc[e];
            float4 a = *(const float4*)(als + s*4);
            e0 = __expf(lrelu(a.x + adv.x));
            e1 = __expf(lrelu(a.y + adv.y));
            e2 = __expf(lrelu(a.z + adv.z));
            e3 = __expf(lrelu(a.w + adv.w));
        }
        dp0 += e0; dp1 += e1; dp2 += e2; dp3 += e3;
        wlds[wid][lane] = make_float4(e0, e1, e2, e3);   // same-wave produce/consume
        slds[wid][lane] = s;
        int cn = min(64, end - c64);
        for (int qb = 0; qb < cn; qb += 16){
            int sA = slds[wid][qb + gq],      sB = slds[wid][qb + 4 + gq];
            int sC = slds[wid][qb + 8 + gq],  sD = slds[wid][qb + 12 + gq];
            float4 wA = wlds[wid][qb + gq],     wB = wlds[wid][qb + 4 + gq];
            float4 wC = wlds[wid][qb + 8 + gq], wD = wlds[wid][qb + 12 + gq];
            float4 hA = *(const float4*)(hin + (size_t)sA*64 + cb*4);
            float4 hB = *(const float4*)(hin + (size_t)sB*64 + cb*4);
            float4 hC = *(const float4*)(hin + (size_t)sC*64 + cb*4);
            float4 hD = *(const float4*)(hin + (size_t)sD*64 + cb*4);
            acc0.x += wA.x*hA.x + wB.x*hB.x + wC.x*hC.x + wD.x*hD.x;
            acc0.y += wA.x*hA.y + wB.x*hB.y + wC.x*hC.y + wD.x*hD.y;
            acc0.z += wA.x*hA.z + wB.x*hB.z + wC.x*hC.z + wD.x*hD.z;
            acc0.w += wA.x*hA.w + wB.x*hB.w + wC.x*hC.w + wD.x*hD.w;
            acc1.x += wA.y*hA.x + wB.y*hB.x + wC.y*hC.x + wD.y*hD.x;
            acc1.y += wA.y*hA.y + wB.y*hB.y + wC.y*hC.y + wD.y*hD.y;
            acc1.z += wA.y*hA.z + wB.y*hB.z + wC.y*hC.z + wD.y*hD.z;
            acc1.w += wA.y*hA.w + wB.y*hB.w + wC.y*hC.w + wD.y*hD.w;
            acc2.x += wA.z*hA.x + wB.z*hB.x + wC.z*hC.x + wD.z*hD.x;
            acc2.y += wA.z*hA.y + wB.z*hB.y + wC.z*hC.y + wD.z*hD.y;
            acc2.z += wA.z*hA.z + wB.z*hB.z + wC.z*hC.z + wD.z*hD.z;
            acc2.w += wA.z*hA.w + wB.z*hB.w + wC.z*hC.w + wD.z*hD.w;
            acc3.x += wA.w*hA.x + wB.w*hB.x + wC.w*hC.x + wD.w*hD.x;
            acc3.y += wA.w*hA.y + wB.w*hB.y + wC.w*hC.y + wD.w*hD.y;
            acc3.z += wA.w*hA.z + wB.w*hB.z + wC.w*hC.z + wD.w*hD.z;
            acc3.w += wA.w*hA.w + wB.w*hB.w + wC.w*hC.w + wD.w*hD.w;
        }
    }
    #pragma unroll
    for (int m = 1; m < 64; m <<= 1){
        dp0 += __shfl_xor(dp0, m); dp1 += __shfl_xor(dp1, m);
        dp2 += __shfl_xor(dp2, m); dp3 += __shfl_xor(dp3, m);
    }
    #pragma unroll
    for (int m = 16; m < 64; m <<= 1){
        acc0.x += __shfl_xor(acc0.x, m); acc0.y += __shfl_xor(acc0.y, m);
        acc0.z += __shfl_xor(acc0.z, m); acc0.w += __shfl_xor(acc0.w, m);
        acc1.x += __shfl_xor(acc1.x, m); acc1.y += __shfl_xor(acc1.y, m);
        acc1.z += __shfl_xor(acc1.z, m); acc1.w += __shfl_xor(acc1.w, m);
        acc2.x += __shfl_xor(acc2.x, m); acc2.y += __shfl_xor(acc2.y, m);
        acc2.z += __shfl_xor(acc2.z, m); acc2.w += __shfl_xor(acc2.w, m);
        acc3.x += __shfl_xor(acc3.x, m); acc3.y += __shfl_xor(acc3.y, m);
        acc3.z += __shfl_xor(acc3.z, m); acc3.w += __shfl_xor(acc3.w, m);
    }
    if (lane < 16){
        float r0 = 1.f/(v0 + dp0), r1 = 1.f/(v1 + dp1);
        float r2 = 1.f/(v2 + dp2), r3 = 1.f/(v3 + dp3);
        *(float4*)&ysh[wid*256 +   0 + cb*4] = make_float4(acc0.x*r0, acc0.y*r0, acc0.z*r0, acc0.w*r0);
        *(float4*)&ysh[wid*256 +  64 + cb*4] = make_float4(acc1.x*r1, acc1.y*r1, acc1.z*r1, acc1.w*r1);
        *(float4*)&ysh[wid*256 + 128 + cb*4] = make_float4(acc2.x*r2, acc2.y*r2, acc2.z*r2, acc2.w*r2);
        *(float4*)&ysh[wid*256 + 192 + cb*4] = make_float4(acc3.x*r3, acc3.y*r3, acc3.z*r3, acc3.w*r3);
    }
    __syncthreads();
    // cooperative GEMM: wave wid covers j in [wid*64, wid*64+64) for all 4 nodes
    float a0 = 0.f, a1 = 0.f, a2 = 0.f, a3 = 0.f;
    int jbase = wid*64;
    #pragma unroll 4
    for (int jj = 0; jj < 64; jj += 4){
        int jb = jbase + jj;
        float4 y0 = *(const float4*)&ysh[0*256 + jb];
        float4 y1 = *(const float4*)&ysh[1*256 + jb];
        float4 y2 = *(const float4*)&ysh[2*256 + jb];
        float4 y3 = *(const float4*)&ysh[3*256 + jb];
        float w0 = W3p[(jb    )*64 + lane];
        float w1 = W3p[(jb + 1)*64 + lane];
        float w2 = W3p[(jb + 2)*64 + lane];
        float w3 = W3p[(jb + 3)*64 + lane];
        a0 += y0.x*w0 + y0.y*w1 + y0.z*w2 + y0.w*w3;
        a1 += y1.x*w0 + y1.y*w1 + y1.z*w2 + y1.w*w3;
        a2 += y2.x*w0 + y2.y*w1 + y2.z*w2 + y2.w*w3;
        a3 += y3.x*w0 + y3.y*w1 + y3.z*w2 + y3.w*w3;
    }
    red[wid][0][lane] = a0;
    red[wid][1][lane] = a1;
    red[wid][2][lane] = a2;
    red[wid][3][lane] = a3;
    __syncthreads();
    // wave wid finalizes node n0+wid: BN then classifier MLP
    float val = red[0][wid][lane] + red[1][wid][lane] +
                red[2][wid][lane] + red[3][wid][lane] + b[lane];
    val = g[lane]*(val - bm[lane])*rsqrtf(bv[lane] + 1e-5f) + bb[lane];
    ysc[wid][lane] = val;            // same-wave produce/consume
    int u = lane >> 1, p = lane & 1; // 2 lanes per hidden unit
    float hsum = 0.f;
    #pragma unroll 8
    for (int kk = 0; kk < 32; ++kk){
        int k = p*32 + kk;
        hsum += ysc[wid][k] * cls1[k*32 + u];
    }
    hsum += __shfl_xor(hsum, 1);
    float contrib = 0.f;
    if (p == 0){
        float hv = clb[u] + hsum;
        hv = hv > 0.f ? hv : expm1f(hv);
        contrib = hv * clw2[u];
    }
    #pragma unroll
    for (int m = 2; m < 64; m <<= 1) contrib += __shfl_xor(contrib, m);
    if (lane == 0 && valid) dout[n0 + wid] = contrib + cb2[0];
}

extern "C" void kernel_launch(void* const* d_in, const int* in_sizes, int n_in,
                              void* d_out, int out_size, void* d_ws, size_t ws_size,
                              hipStream_t stream) {
    const float* x    = (const float*)d_in[0];
    const int*   ei   = (const int*)  d_in[1];
    const float* W1   = (const float*)d_in[2];
    const float* a1s  = (const float*)d_in[3];
    const float* a1d  = (const float*)d_in[4];
    const float* b1   = (const float*)d_in[5];
    const float* W2   = (const float*)d_in[6];
    const float* a2s  = (const float*)d_in[7];
    const float* a2d  = (const float*)d_in[8];
    const float* b2   = (const float*)d_in[9];
    const float* W3   = (const float*)d_in[10];
    const float* a3s  = (const float*)d_in[11];
    const float* a3d  = (const float*)d_in[12];
    const float* b3   = (const float*)d_in[13];
    const float* bn1g = (const float*)d_in[14];
    const float* bn1b = (const float*)d_in[15];
    const float* bn1m = (const float*)d_in[16];
    const float* bn1v = (const float*)d_in[17];
    const float* bn2g = (const float*)d_in[18];
    const float* bn2b = (const float*)d_in[19];
    const float* bn2m = (const float*)d_in[20];
    const float* bn2v = (const float*)d_in[21];
    const float* bn3g = (const float*)d_in[22];
    const float* bn3b = (const float*)d_in[23];
    const float* bn3m = (const float*)d_in[24];
    const float* bn3v = (const float*)d_in[25];
    const float* cW1  = (const float*)d_in[26];
    const float* cb1  = (const float*)d_in[27];
    const float* cW2  = (const float*)d_in[28];
    const float* cb2  = (const float*)d_in[29];

    const int N = in_sizes[0] / 128;
    const int E = in_sizes[1] / 2;

    // ws layout (floats): h[64N] h2[64N] hin[64N] als[4N] ald[4N] als2[4N] ald2[4N]
    //                     als3[4N] ald3[4N] ws3[256] wd3[256] W3p[16384]
    // ints: deg[N] row_off[N+1] cursor[N] ssrc[E] bsum[NB]
    float* h    = (float*)d_ws;
    float* h2   = h    + (size_t)N*64;
    float* hin  = h2   + (size_t)N*64;
    float* als  = hin  + (size_t)N*64;
    float* ald  = als  + (size_t)N*4;
    float* als2 = ald  + (size_t)N*4;
    float* ald2 = als2 + (size_t)N*4;
    float* als3 = ald2 + (size_t)N*4;
    float* ald3 = als3 + (size_t)N*4;
    float* ws3  = ald3 + (size_t)N*4;
    float* wd3  = ws3  + 256;
    float* W3p  = wd3  + 256;
    int* deg     = (int*)(W3p + 16384);
    int* row_off = deg + N;
    int* cursor  = row_off + (N + 1);
    int* ssrc    = cursor + N;
    int* bsum    = ssrc + E;

    const int B = 256;
    int gN  = (N + B-1)/B;
    int gE  = (E + B-1)/B;
    int NB  = (N + 1023)/1024;
    int gN4 = (N + 3)/4;

    // ---- CSR build (dst-grouped src lists), reused by all 3 layers ----
    zero_i32<<<gN, B, 0, stream>>>(deg, N);
    count_deg<<<gE, B, 0, stream>>>(ei, deg, E);
    deg_bsum<<<NB, B, 0, stream>>>(deg, bsum, N);
    scan_write<<<NB, B, 0, stream>>>(deg, bsum, row_off, cursor, N, E);
    fill_csr<<<gE, B, 0, stream>>>(ei, cursor, ssrc, E);
    prep_l3<<<1, 256, 0, stream>>>(W3, a3s, a3d, ws3, wd3, W3p);

    // ---- layer 1 transform (IC=128) ----
    gemm_gat<128><<<gN4, B, 0, stream>>>(x, W1, a1s, a1d, h, als, ald, N);

    // ---- layer-1 aggregation + fused layer-2 transform ----
    gat_agg16_l1<<<gN4, B, 0, stream>>>(row_off, ssrc, als, ald, h, b1,
                                        bn1g, bn1b, bn1m, bn1v,
                                        W2, a2s, a2d, h2, als2, ald2, N);

    // ---- layer-2 aggregation + layer-3 logits ----
    gat_agg16_l2<<<gN4, B, 0, stream>>>(row_off, ssrc, als2, ald2, h2, b2,
                                        bn2g, bn2b, bn2m, bn2v, hin,
                                        ws3, wd3, als3, ald3, N);

    // ---- layer 3: aggregate hin + coop GEMM + BN + fused classifier ----
    gat_agg3_fused<<<gN4, B, 0, stream>>>(row_off, ssrc, als3, ald3, hin, W3p,
                                          b3, bn3g, bn3b, bn3m, bn3v,
                                          cW1, cb1, cW2, cb2, (float*)d_out, N);
}

// Round 11
// 378.273 us; speedup vs baseline: 1.0293x; 1.0293x over previous
//
#include <hip/hip_runtime.h>

#define HH 4  // heads

__device__ __forceinline__ float lrelu(float v){ return v > 0.f ? v : 0.2f*v; }

// h = X @ W  (W is [IC, 64] row-major), plus per-head attention logits (C=16).
// 256-thread block = 4 waves, one node per wave. Compile-time IC for unroll.
template<int IC>
__global__ void gemm_gat(const float* __restrict__ X, const float* __restrict__ W,
                         const float* __restrict__ a_s, const float* __restrict__ a_d,
                         float* __restrict__ h, float* __restrict__ als, float* __restrict__ ald,
                         int N) {
    int t = threadIdx.x, lane = t & 63, wid = t >> 6;
    int n = blockIdx.x*4 + wid;
    bool valid = n < N;
    int nc = valid ? n : N-1;
    __shared__ float xs[4][IC];
    #pragma unroll
    for (int k = lane; k < IC; k += 64) xs[wid][k] = X[(size_t)nc*IC + k];
    float acc = 0.f;
    #pragma unroll 8
    for (int k = 0; k < IC; ++k) acc += xs[wid][k] * W[k*64 + lane];
    if (valid) h[(size_t)nc*64 + lane] = acc;
    int hh = lane >> 4, c = lane & 15;
    float ps = acc * a_s[hh*16 + c];
    float pd = acc * a_d[hh*16 + c];
    #pragma unroll
    for (int m = 1; m < 16; m <<= 1){ ps += __shfl_xor(ps, m); pd += __shfl_xor(pd, m); }
    if (valid && c == 0){ als[nc*HH + hh] = ps; ald[nc*HH + hh] = pd; }
}

// ---------------- CSR build ----------------

__global__ void zero_i32(int* __restrict__ p, int n){
    int i = blockIdx.x*256 + threadIdx.x;
    if (i < n) p[i] = 0;
}

__global__ void count_deg(const int* __restrict__ ei, int* __restrict__ deg, int E){
    int e = blockIdx.x*256 + threadIdx.x;
    if (e < E) atomicAdd(&deg[ei[E + e]], 1);
}

__global__ void deg_bsum(const int* __restrict__ deg, int* __restrict__ bsum, int N){
    int t = threadIdx.x;
    int base = blockIdx.x*1024 + t*4;
    int s = 0;
    if (base + 3 < N){
        int4 v = *(const int4*)(deg + base);
        s = v.x + v.y + v.z + v.w;
    } else {
        for (int q = 0; q < 4; ++q) if (base + q < N) s += deg[base + q];
    }
    #pragma unroll
    for (int m = 1; m < 64; m <<= 1) s += __shfl_xor(s, m);
    __shared__ int ws[4];
    if ((t & 63) == 0) ws[t >> 6] = s;
    __syncthreads();
    if (t == 0) bsum[blockIdx.x] = ws[0] + ws[1] + ws[2] + ws[3];
}

__global__ void scan_write(const int* __restrict__ deg, const int* __restrict__ bsum,
                           int* __restrict__ row_off, int* __restrict__ cursor, int N, int E){
    int t = threadIdx.x, bid = blockIdx.x, lane = t & 63, w = t >> 6;
    int base = bid*1024 + t*4;
    int v0 = 0, v1 = 0, v2 = 0, v3 = 0;
    if (base + 3 < N){
        int4 v = *(const int4*)(deg + base);
        v0 = v.x; v1 = v.y; v2 = v.z; v3 = v.w;
    } else {
        if (base     < N) v0 = deg[base];
        if (base + 1 < N) v1 = deg[base + 1];
        if (base + 2 < N) v2 = deg[base + 2];
        if (base + 3 < N) v3 = deg[base + 3];
    }
    int s = v0 + v1 + v2 + v3;
    int x = s;
    #pragma unroll
    for (int d = 1; d < 64; d <<= 1){
        int y = __shfl_up(x, d);
        if (lane >= d) x += y;
    }
    __shared__ int wsum[4];
    __shared__ int boff_s;
    if (lane == 63) wsum[w] = x;
    if (t < 64){
        int o = 0;
        for (int i = t; i < bid; i += 64) o += bsum[i];
        #pragma unroll
        for (int m = 1; m < 64; m <<= 1) o += __shfl_xor(o, m);
        if (t == 0) boff_s = o;
    }
    __syncthreads();
    int woff = 0;
    for (int i = 0; i < w; ++i) woff += wsum[i];
    int o = boff_s + woff + (x - s);
    if (base     < N){ row_off[base]     = o; cursor[base]     = o; o += v0; }
    if (base + 1 < N){ row_off[base + 1] = o; cursor[base + 1] = o; o += v1; }
    if (base + 2 < N){ row_off[base + 2] = o; cursor[base + 2] = o; o += v2; }
    if (base + 3 < N){ row_off[base + 3] = o; cursor[base + 3] = o; o += v3; }
    if (t == 0 && bid == 0) row_off[N] = E;
}

__global__ void fill_csr(const int* __restrict__ ei, int* __restrict__ cursor,
                         int* __restrict__ ssrc, int E){
    int e = blockIdx.x*256 + threadIdx.x;
    if (e < E){
        int d = ei[E + e];
        int p = atomicAdd(&cursor[d], 1);
        ssrc[p] = ei[e];
    }
}

// ---------------- layer-3 prep ----------------
__global__ void prep_l3(const float* __restrict__ W3, const float* __restrict__ a3s,
                        const float* __restrict__ a3d, float* __restrict__ ws3,
                        float* __restrict__ wd3, float* __restrict__ W3p){
    int t = threadIdx.x;          // 256 = (hh,k)
    int hh = t >> 6, k = t & 63;
    float ss = 0.f, sd = 0.f;
    for (int c = 0; c < 64; ++c){
        float w = W3[k*256 + hh*64 + c];
        ss += w * a3s[hh*64 + c];
        sd += w * a3d[hh*64 + c];
        W3p[t*64 + c] = 0.25f * w;
    }
    ws3[t] = ss; wd3[t] = sd;
}

// ================= layer-1 aggregation + BN/ELU + FUSED layer-2 transform =================
// 4 nodes/block, one wave per node. Gather: 16 slots per chunk, 4 dwordx4 in flight.
// Self-seed MUST be group-0-only (lane<16): the m=16,32 butterfly sums the 4 groups.
__global__ void gat_agg16_l1(const int* __restrict__ row_off, const int* __restrict__ ssrc,
                             const float* __restrict__ als, const float* __restrict__ ald,
                             const float* __restrict__ h, const float* __restrict__ b,
                             const float* __restrict__ g, const float* __restrict__ bb,
                             const float* __restrict__ bm, const float* __restrict__ bv,
                             const float* __restrict__ W2, const float* __restrict__ a2s,
                             const float* __restrict__ a2d, float* __restrict__ h2,
                             float* __restrict__ als2, float* __restrict__ ald2, int N){
    int t = threadIdx.x, lane = t & 63, wid = t >> 6;
    __shared__ float wl[4][16][4];   // [wave][edge][head]
    __shared__ int   sl[4][16];
    __shared__ __align__(16) float vb[4][64];
    int n = blockIdx.x*4 + wid;
    if (n >= N) return;              // no cross-wave LDS use; safe
    int j  = lane & 15;   // weight-phase edge slot
    int hh = lane >> 4;   // weight-phase head
    int cb = lane & 15;   // channel block (4 ch)
    int gq = lane >> 4;   // gather edge-group
    int hd = cb >> 2;     // head of my channels
    float ad_w = ald[n*HH + hh];
    float v_hd = __expf(lrelu(als[n*HH + hd] + ald[n*HH + hd]));
    int beg = row_off[n], end = row_off[n+1];
    float4 acc = make_float4(0.f, 0.f, 0.f, 0.f);
    if (lane < 16){   // seed self-loop in group 0 ONLY (butterfly sums groups)
        float4 hs = *(const float4*)(h + (size_t)n*64 + cb*4);
        acc.x = v_hd*hs.x; acc.y = v_hd*hs.y; acc.z = v_hd*hs.z; acc.w = v_hd*hs.w;
    }
    float denp = 0.f;
    for (int c16 = beg; c16 < end; c16 += 16){
        int e = c16 + j;
        int s = n; float ev = 0.f;
        if (e < end){ s = ssrc[e]; ev = __expf(lrelu(als[s*HH + hh] + ad_w)); }
        denp += ev;
        wl[wid][j][hh] = ev;
        if (hh == 0) sl[wid][j] = s;
        // all 16 slots unconditionally (dead slots: w=0, s=self -> L1-hot)
        int   s0 = sl[wid][gq],     s1 = sl[wid][4+gq];
        int   s2 = sl[wid][8+gq],   s3 = sl[wid][12+gq];
        float w0 = wl[wid][gq][hd], w1 = wl[wid][4+gq][hd];
        float w2 = wl[wid][8+gq][hd], w3 = wl[wid][12+gq][hd];
        float4 h0 = *(const float4*)(h + (size_t)s0*64 + cb*4);
        float4 h1 = *(const float4*)(h + (size_t)s1*64 + cb*4);
        float4 h2v = *(const float4*)(h + (size_t)s2*64 + cb*4);
        float4 h3 = *(const float4*)(h + (size_t)s3*64 + cb*4);
        acc.x += w0*h0.x + w1*h1.x + w2*h2v.x + w3*h3.x;
        acc.y += w0*h0.y + w1*h1.y + w2*h2v.y + w3*h3.y;
        acc.z += w0*h0.z + w1*h1.z + w2*h2v.z + w3*h3.z;
        acc.w += w0*h0.w + w1*h1.w + w2*h2v.w + w3*h3.w;
    }
    #pragma unroll
    for (int m = 1; m < 16; m <<= 1) denp += __shfl_xor(denp, m);
    float den = __shfl(denp, hd << 4) + v_hd;
    #pragma unroll
    for (int m = 16; m < 64; m <<= 1){
        acc.x += __shfl_xor(acc.x, m); acc.y += __shfl_xor(acc.y, m);
        acc.z += __shfl_xor(acc.z, m); acc.w += __shfl_xor(acc.w, m);
    }
    float4 bb4 = *(const float4*)(b  + cb*4);
    float4 gg4 = *(const float4*)(g  + cb*4);
    float4 be4 = *(const float4*)(bb + cb*4);
    float4 bm4 = *(const float4*)(bm + cb*4);
    float4 bv4 = *(const float4*)(bv + cb*4);
    float4 val;
    val.x = gg4.x*(acc.x/den + bb4.x - bm4.x)*rsqrtf(bv4.x + 1e-5f) + be4.x;
    val.y = gg4.y*(acc.y/den + bb4.y - bm4.y)*rsqrtf(bv4.y + 1e-5f) + be4.y;
    val.z = gg4.z*(acc.z/den + bb4.z - bm4.z)*rsqrtf(bv4.z + 1e-5f) + be4.z;
    val.w = gg4.w*(acc.w/den + bb4.w - bm4.w)*rsqrtf(bv4.w + 1e-5f) + be4.w;
    val.x = val.x > 0.f ? val.x : expm1f(val.x);
    val.y = val.y > 0.f ? val.y : expm1f(val.y);
    val.z = val.z > 0.f ? val.z : expm1f(val.z);
    val.w = val.w > 0.f ? val.w : expm1f(val.w);
    if (lane < 16) *(float4*)&vb[wid][cb*4] = val;   // same-wave produce/consume
    // ---- fused layer-2 transform: h2row[lane] = vb . W2[:,lane] ----
    float acc2 = 0.f;
    #pragma unroll 8
    for (int k = 0; k < 64; ++k) acc2 += vb[wid][k] * W2[k*64 + lane];
    h2[(size_t)n*64 + lane] = acc2;
    float ps = acc2 * a2s[hh*16 + j];
    float pd = acc2 * a2d[hh*16 + j];
    #pragma unroll
    for (int m = 1; m < 16; m <<= 1){ ps += __shfl_xor(ps, m); pd += __shfl_xor(pd, m); }
    if (j == 0){ als2[n*HH + hh] = ps; ald2[n*HH + hh] = pd; }
}

// ---------------- layer-2 aggregation + BN/ELU + layer-3 logits ----------------
__global__ void gat_agg16_l2(const int* __restrict__ row_off, const int* __restrict__ ssrc,
                             const float* __restrict__ als, const float* __restrict__ ald,
                             const float* __restrict__ h, const float* __restrict__ b,
                             const float* __restrict__ g, const float* __restrict__ bb,
                             const float* __restrict__ bm, const float* __restrict__ bv,
                             float* __restrict__ out,
                             const float* __restrict__ ws3, const float* __restrict__ wd3,
                             float* __restrict__ als3, float* __restrict__ ald3, int N){
    int t = threadIdx.x, lane = t & 63, wid = t >> 6;
    int n = blockIdx.x*4 + wid;
    if (n >= N) return;
    __shared__ float wl[4][16][4];
    __shared__ int   sl[4][16];
    int j  = lane & 15;
    int hh = lane >> 4;
    int cb = lane & 15;
    int gq = lane >> 4;
    int hd = cb >> 2;
    float ad_w = ald[n*HH + hh];
    float v_hd = __expf(lrelu(als[n*HH + hd] + ald[n*HH + hd]));
    int beg = row_off[n], end = row_off[n+1];
    float4 acc = make_float4(0.f, 0.f, 0.f, 0.f);
    if (lane < 16){   // seed self-loop in group 0 ONLY
        float4 hs = *(const float4*)(h + (size_t)n*64 + cb*4);
        acc.x = v_hd*hs.x; acc.y = v_hd*hs.y; acc.z = v_hd*hs.z; acc.w = v_hd*hs.w;
    }
    float denp = 0.f;
    for (int c16 = beg; c16 < end; c16 += 16){
        int e = c16 + j;
        int s = n; float ev = 0.f;
        if (e < end){ s = ssrc[e]; ev = __expf(lrelu(als[s*HH + hh] + ad_w)); }
        denp += ev;
        wl[wid][j][hh] = ev;
        if (hh == 0) sl[wid][j] = s;
        int   s0 = sl[wid][gq],     s1 = sl[wid][4+gq];
        int   s2 = sl[wid][8+gq],   s3 = sl[wid][12+gq];
        float w0 = wl[wid][gq][hd], w1 = wl[wid][4+gq][hd];
        float w2 = wl[wid][8+gq][hd], w3 = wl[wid][12+gq][hd];
        float4 h0 = *(const float4*)(h + (size_t)s0*64 + cb*4);
        float4 h1 = *(const float4*)(h + (size_t)s1*64 + cb*4);
        float4 h2v = *(const float4*)(h + (size_t)s2*64 + cb*4);
        float4 h3 = *(const float4*)(h + (size_t)s3*64 + cb*4);
        acc.x += w0*h0.x + w1*h1.x + w2*h2v.x + w3*h3.x;
        acc.y += w0*h0.y + w1*h1.y + w2*h2v.y + w3*h3.y;
        acc.z += w0*h0.z + w1*h1.z + w2*h2v.z + w3*h3.z;
        acc.w += w0*h0.w + w1*h1.w + w2*h2v.w + w3*h3.w;
    }
    #pragma unroll
    for (int m = 1; m < 16; m <<= 1) denp += __shfl_xor(denp, m);
    float den = __shfl(denp, hd << 4) + v_hd;
    #pragma unroll
    for (int m = 16; m < 64; m <<= 1){
        acc.x += __shfl_xor(acc.x, m); acc.y += __shfl_xor(acc.y, m);
        acc.z += __shfl_xor(acc.z, m); acc.w += __shfl_xor(acc.w, m);
    }
    float4 bb4 = *(const float4*)(b  + cb*4);
    float4 gg4 = *(const float4*)(g  + cb*4);
    float4 be4 = *(const float4*)(bb + cb*4);
    float4 bm4 = *(const float4*)(bm + cb*4);
    float4 bv4 = *(const float4*)(bv + cb*4);
    float4 val;
    val.x = gg4.x*(acc.x/den + bb4.x - bm4.x)*rsqrtf(bv4.x + 1e-5f) + be4.x;
    val.y = gg4.y*(acc.y/den + bb4.y - bm4.y)*rsqrtf(bv4.y + 1e-5f) + be4.y;
    val.z = gg4.z*(acc.z/den + bb4.z - bm4.z)*rsqrtf(bv4.z + 1e-5f) + be4.z;
    val.w = gg4.w*(acc.w/den + bb4.w - bm4.w)*rsqrtf(bv4.w + 1e-5f) + be4.w;
    val.x = val.x > 0.f ? val.x : expm1f(val.x);
    val.y = val.y > 0.f ? val.y : expm1f(val.y);
    val.z = val.z > 0.f ? val.z : expm1f(val.z);
    val.w = val.w > 0.f ? val.w : expm1f(val.w);
    if (lane < 16) *(float4*)(out + (size_t)n*64 + cb*4) = val;
    // layer-3 logits: group gq computes head gq from full row
    float4 w_s = *(const float4*)(ws3 + gq*64 + cb*4);
    float4 w_d = *(const float4*)(wd3 + gq*64 + cb*4);
    float ps = val.x*w_s.x + val.y*w_s.y + val.z*w_s.z + val.w*w_s.w;
    float pd = val.x*w_d.x + val.y*w_d.y + val.z*w_d.z + val.w*w_d.w;
    #pragma unroll
    for (int m = 1; m < 16; m <<= 1){ ps += __shfl_xor(ps, m); pd += __shfl_xor(pd, m); }
    if (cb == 0){ als3[n*HH + gq] = ps; ald3[n*HH + gq] = pd; }
}

// ===== layer-3: aggregate hin (4 heads) + coop GEMM W3p + BN + FUSED classifier =====
// LDS diet: red aliases wlds (dead after barrier), ysc aliases slds; cW1 read from
// global (8 KB, identical for all blocks -> L1-hot). Total LDS ~9.2 KB.
__global__ void gat_agg3_fused(const int* __restrict__ row_off, const int* __restrict__ ssrc,
                               const float* __restrict__ als, const float* __restrict__ ald,
                               const float* __restrict__ hin, const float* __restrict__ W3p,
                               const float* __restrict__ b, const float* __restrict__ g,
                               const float* __restrict__ bb, const float* __restrict__ bm,
                               const float* __restrict__ bv,
                               const float* __restrict__ cW1, const float* __restrict__ cb1,
                               const float* __restrict__ cW2, const float* __restrict__ cb2,
                               float* __restrict__ dout, int N){
    int t = threadIdx.x, lane = t & 63, wid = t >> 6;
    int n0 = blockIdx.x*4;
    int n = min(n0 + wid, N-1);          // clamp; no early return (syncthreads below)
    bool valid = (n0 + wid) < N;
    __shared__ __align__(16) float4 wlds[4][64];   // 4 KB; aliased as red after barrier 1
    __shared__ int slds[4][64];                    // 1 KB; aliased as ysc after barrier 2
    __shared__ __align__(16) float ysh[4*256];     // 4 KB
    float (*red)[4][64] = (float(*)[4][64])wlds;   // [wave][node][lane]
    float (*ysc)[64]    = (float(*)[64])slds;      // [wave][lane]
    int cb = lane & 15, gq = lane >> 4;
    float4 adv = *(const float4*)(ald + n*4);
    float4 av  = *(const float4*)(als + n*4);
    float v0 = __expf(lrelu(av.x + adv.x)), v1 = __expf(lrelu(av.y + adv.y));
    float v2 = __expf(lrelu(av.z + adv.z)), v3 = __expf(lrelu(av.w + adv.w));
    int beg = row_off[n], end = row_off[n+1];
    float4 acc0 = make_float4(0,0,0,0), acc1 = acc0, acc2 = acc0, acc3 = acc0;
    if (lane < 16){   // seed self-loop in group 0 ONLY
        float4 hs = *(const float4*)(hin + (size_t)n*64 + cb*4);
        acc0.x = v0*hs.x; acc0.y = v0*hs.y; acc0.z = v0*hs.z; acc0.w = v0*hs.w;
        acc1.x = v1*hs.x; acc1.y = v1*hs.y; acc1.z = v1*hs.z; acc1.w = v1*hs.w;
        acc2.x = v2*hs.x; acc2.y = v2*hs.y; acc2.z = v2*hs.z; acc2.w = v2*hs.w;
        acc3.x = v3*hs.x; acc3.y = v3*hs.y; acc3.z = v3*hs.z; acc3.w = v3*hs.w;
    }
    float dp0 = 0.f, dp1 = 0.f, dp2 = 0.f, dp3 = 0.f;
    for (int c64 = beg; c64 < end; c64 += 64){
        int e = c64 + lane;
        int s = n; float e0 = 0.f, e1 = 0.f, e2 = 0.f, e3 = 0.f;
        if (e < end){
            s = ssrc[e];
            float4 a = *(const float4*)(als + s*4);
            e0 = __expf(lrelu(a.x + adv.x));
            e1 = __expf(lrelu(a.y + adv.y));
            e2 = __expf(lrelu(a.z + adv.z));
            e3 = __expf(lrelu(a.w + adv.w));
        }
        dp0 += e0; dp1 += e1; dp2 += e2; dp3 += e3;
        wlds[wid][lane] = make_float4(e0, e1, e2, e3);   // same-wave produce/consume
        slds[wid][lane] = s;
        int cn = min(64, end - c64);
        for (int qb = 0; qb < cn; qb += 16){
            int sA = slds[wid][qb + gq],      sB = slds[wid][qb + 4 + gq];
            int sC = slds[wid][qb + 8 + gq],  sD = slds[wid][qb + 12 + gq];
            float4 wA = wlds[wid][qb + gq],     wB = wlds[wid][qb + 4 + gq];
            float4 wC = wlds[wid][qb + 8 + gq], wD = wlds[wid][qb + 12 + gq];
            float4 hA = *(const float4*)(hin + (size_t)sA*64 + cb*4);
            float4 hB = *(const float4*)(hin + (size_t)sB*64 + cb*4);
            float4 hC = *(const float4*)(hin + (size_t)sC*64 + cb*4);
            float4 hD = *(const float4*)(hin + (size_t)sD*64 + cb*4);
            acc0.x += wA.x*hA.x + wB.x*hB.x + wC.x*hC.x + wD.x*hD.x;
            acc0.y += wA.x*hA.y + wB.x*hB.y + wC.x*hC.y + wD.x*hD.y;
            acc0.z += wA.x*hA.z + wB.x*hB.z + wC.x*hC.z + wD.x*hD.z;
            acc0.w += wA.x*hA.w + wB.x*hB.w + wC.x*hC.w + wD.x*hD.w;
            acc1.x += wA.y*hA.x + wB.y*hB.x + wC.y*hC.x + wD.y*hD.x;
            acc1.y += wA.y*hA.y + wB.y*hB.y + wC.y*hC.y + wD.y*hD.y;
            acc1.z += wA.y*hA.z + wB.y*hB.z + wC.y*hC.z + wD.y*hD.z;
            acc1.w += wA.y*hA.w + wB.y*hB.w + wC.y*hC.w + wD.y*hD.w;
            acc2.x += wA.z*hA.x + wB.z*hB.x + wC.z*hC.x + wD.z*hD.x;
            acc2.y += wA.z*hA.y + wB.z*hB.y + wC.z*hC.y + wD.z*hD.y;
            acc2.z += wA.z*hA.z + wB.z*hB.z + wC.z*hC.z + wD.z*hD.z;
            acc2.w += wA.z*hA.w + wB.z*hB.w + wC.z*hC.w + wD.z*hD.w;
            acc3.x += wA.w*hA.x + wB.w*hB.x + wC.w*hC.x + wD.w*hD.x;
            acc3.y += wA.w*hA.y + wB.w*hB.y + wC.w*hC.y + wD.w*hD.y;
            acc3.z += wA.w*hA.z + wB.w*hB.z + wC.w*hC.z + wD.w*hD.z;
            acc3.w += wA.w*hA.w + wB.w*hB.w + wC.w*hC.w + wD.w*hD.w;
        }
    }
    #pragma unroll
    for (int m = 1; m < 64; m <<= 1){
        dp0 += __shfl_xor(dp0, m); dp1 += __shfl_xor(dp1, m);
        dp2 += __shfl_xor(dp2, m); dp3 += __shfl_xor(dp3, m);
    }
    #pragma unroll
    for (int m = 16; m < 64; m <<= 1){
        acc0.x += __shfl_xor(acc0.x, m); acc0.y += __shfl_xor(acc0.y, m);
        acc0.z += __shfl_xor(acc0.z, m); acc0.w += __shfl_xor(acc0.w, m);
        acc1.x += __shfl_xor(acc1.x, m); acc1.y += __shfl_xor(acc1.y, m);
        acc1.z += __shfl_xor(acc1.z, m); acc1.w += __shfl_xor(acc1.w, m);
        acc2.x += __shfl_xor(acc2.x, m); acc2.y += __shfl_xor(acc2.y, m);
        acc2.z += __shfl_xor(acc2.z, m); acc2.w += __shfl_xor(acc2.w, m);
        acc3.x += __shfl_xor(acc3.x, m); acc3.y += __shfl_xor(acc3.y, m);
        acc3.z += __shfl_xor(acc3.z, m); acc3.w += __shfl_xor(acc3.w, m);
    }
    if (lane < 16){
        float r0 = 1.f/(v0 + dp0), r1 = 1.f/(v1 + dp1);
        float r2 = 1.f/(v2 + dp2), r3 = 1.f/(v3 + dp3);
        *(float4*)&ysh[wid*256 +   0 + cb*4] = make_float4(acc0.x*r0, acc0.y*r0, acc0.z*r0, acc0.w*r0);
        *(float4*)&ysh[wid*256 +  64 + cb*4] = make_float4(acc1.x*r1, acc1.y*r1, acc1.z*r1, acc1.w*r1);
        *(float4*)&ysh[wid*256 + 128 + cb*4] = make_float4(acc2.x*r2, acc2.y*r2, acc2.z*r2, acc2.w*r2);
        *(float4*)&ysh[wid*256 + 192 + cb*4] = make_float4(acc3.x*r3, acc3.y*r3, acc3.z*r3, acc3.w*r3);
    }
    __syncthreads();   // after this, wlds/slds are dead -> reuse as red/ysc
    // cooperative GEMM: wave wid covers j in [wid*64, wid*64+64) for all 4 nodes
    float a0 = 0.f, a1 = 0.f, a2 = 0.f, a3 = 0.f;
    int jbase = wid*64;
    #pragma unroll 4
    for (int jj = 0; jj < 64; jj += 4){
        int jb = jbase + jj;
        float4 y0 = *(const float4*)&ysh[0*256 + jb];
        float4 y1 = *(const float4*)&ysh[1*256 + jb];
        float4 y2 = *(const float4*)&ysh[2*256 + jb];
        float4 y3 = *(const float4*)&ysh[3*256 + jb];
        float w0 = W3p[(jb    )*64 + lane];
        float w1 = W3p[(jb + 1)*64 + lane];
        float w2 = W3p[(jb + 2)*64 + lane];
        float w3 = W3p[(jb + 3)*64 + lane];
        a0 += y0.x*w0 + y0.y*w1 + y0.z*w2 + y0.w*w3;
        a1 += y1.x*w0 + y1.y*w1 + y1.z*w2 + y1.w*w3;
        a2 += y2.x*w0 + y2.y*w1 + y2.z*w2 + y2.w*w3;
        a3 += y3.x*w0 + y3.y*w1 + y3.z*w2 + y3.w*w3;
    }
    red[wid][0][lane] = a0;
    red[wid][1][lane] = a1;
    red[wid][2][lane] = a2;
    red[wid][3][lane] = a3;
    __syncthreads();
    // wave wid finalizes node n0+wid: BN then classifier MLP (cW1 global, L1-hot)
    float val = red[0][wid][lane] + red[1][wid][lane] +
                red[2][wid][lane] + red[3][wid][lane] + b[lane];
    val = g[lane]*(val - bm[lane])*rsqrtf(bv[lane] + 1e-5f) + bb[lane];
    ysc[wid][lane] = val;            // same-wave produce/consume (aliased slds)
    int u = lane >> 1, p = lane & 1; // 2 lanes per hidden unit
    float hsum = 0.f;
    #pragma unroll 8
    for (int kk = 0; kk < 32; ++kk){
        int k = p*32 + kk;
        hsum += ysc[wid][k] * cW1[k*32 + u];
    }
    hsum += __shfl_xor(hsum, 1);
    float contrib = 0.f;
    if (p == 0){
        float hv = cb1[u] + hsum;
        hv = hv > 0.f ? hv : expm1f(hv);
        contrib = hv * cW2[u];
    }
    #pragma unroll
    for (int m = 2; m < 64; m <<= 1) contrib += __shfl_xor(contrib, m);
    if (lane == 0 && valid) dout[n0 + wid] = contrib + cb2[0];
}

extern "C" void kernel_launch(void* const* d_in, const int* in_sizes, int n_in,
                              void* d_out, int out_size, void* d_ws, size_t ws_size,
                              hipStream_t stream) {
    const float* x    = (const float*)d_in[0];
    const int*   ei   = (const int*)  d_in[1];
    const float* W1   = (const float*)d_in[2];
    const float* a1s  = (const float*)d_in[3];
    const float* a1d  = (const float*)d_in[4];
    const float* b1   = (const float*)d_in[5];
    const float* W2   = (const float*)d_in[6];
    const float* a2s  = (const float*)d_in[7];
    const float* a2d  = (const float*)d_in[8];
    const float* b2   = (const float*)d_in[9];
    const float* W3   = (const float*)d_in[10];
    const float* a3s  = (const float*)d_in[11];
    const float* a3d  = (const float*)d_in[12];
    const float* b3   = (const float*)d_in[13];
    const float* bn1g = (const float*)d_in[14];
    const float* bn1b = (const float*)d_in[15];
    const float* bn1m = (const float*)d_in[16];
    const float* bn1v = (const float*)d_in[17];
    const float* bn2g = (const float*)d_in[18];
    const float* bn2b = (const float*)d_in[19];
    const float* bn2m = (const float*)d_in[20];
    const float* bn2v = (const float*)d_in[21];
    const float* bn3g = (const float*)d_in[22];
    const float* bn3b = (const float*)d_in[23];
    const float* bn3m = (const float*)d_in[24];
    const float* bn3v = (const float*)d_in[25];
    const float* cW1  = (const float*)d_in[26];
    const float* cb1  = (const float*)d_in[27];
    const float* cW2  = (const float*)d_in[28];
    const float* cb2  = (const float*)d_in[29];

    const int N = in_sizes[0] / 128;
    const int E = in_sizes[1] / 2;

    // ws layout (floats): h[64N] h2[64N] hin[64N] als[4N] ald[4N] als2[4N] ald2[4N]
    //                     als3[4N] ald3[4N] ws3[256] wd3[256] W3p[16384]
    // ints: deg[N] row_off[N+1] cursor[N] ssrc[E] bsum[NB]
    float* h    = (float*)d_ws;
    float* h2   = h    + (size_t)N*64;
    float* hin  = h2   + (size_t)N*64;
    float* als  = hin  + (size_t)N*64;
    float* ald  = als  + (size_t)N*4;
    float* als2 = ald  + (size_t)N*4;
    float* ald2 = als2 + (size_t)N*4;
    float* als3 = ald2 + (size_t)N*4;
    float* ald3 = als3 + (size_t)N*4;
    float* ws3  = ald3 + (size_t)N*4;
    float* wd3  = ws3  + 256;
    float* W3p  = wd3  + 256;
    int* deg     = (int*)(W3p + 16384);
    int* row_off = deg + N;
    int* cursor  = row_off + (N + 1);
    int* ssrc    = cursor + N;
    int* bsum    = ssrc + E;

    const int B = 256;
    int gN  = (N + B-1)/B;
    int gE  = (E + B-1)/B;
    int NB  = (N + 1023)/1024;
    int gN4 = (N + 3)/4;

    // ---- CSR build (dst-grouped src lists), reused by all 3 layers ----
    zero_i32<<<gN, B, 0, stream>>>(deg, N);
    count_deg<<<gE, B, 0, stream>>>(ei, deg, E);
    deg_bsum<<<NB, B, 0, stream>>>(deg, bsum, N);
    scan_write<<<NB, B, 0, stream>>>(deg, bsum, row_off, cursor, N, E);
    fill_csr<<<gE, B, 0, stream>>>(ei, cursor, ssrc, E);
    prep_l3<<<1, 256, 0, stream>>>(W3, a3s, a3d, ws3, wd3, W3p);

    // ---- layer 1 transform (IC=128) ----
    gemm_gat<128><<<gN4, B, 0, stream>>>(x, W1, a1s, a1d, h, als, ald, N);

    // ---- layer-1 aggregation + fused layer-2 transform ----
    gat_agg16_l1<<<gN4, B, 0, stream>>>(row_off, ssrc, als, ald, h, b1,
                                        bn1g, bn1b, bn1m, bn1v,
                                        W2, a2s, a2d, h2, als2, ald2, N);

    // ---- layer-2 aggregation + layer-3 logits ----
    gat_agg16_l2<<<gN4, B, 0, stream>>>(row_off, ssrc, als2, ald2, h2, b2,
                                        bn2g, bn2b, bn2m, bn2v, hin,
                                        ws3, wd3, als3, ald3, N);

    // ---- layer 3: aggregate hin + coop GEMM + BN + fused classifier ----
    gat_agg3_fused<<<gN4, B, 0, stream>>>(row_off, ssrc, als3, ald3, hin, W3p,
                                          b3, bn3g, bn3b, bn3m, bn3v,
                                          cW1, cb1, cW2, cb2, (float*)d_out, N);
}